// Round 3
// baseline (181.641 us; speedup 1.0000x reference)
//
#include <hip/hip_runtime.h>
#include <hip/hip_fp16.h>

#define NNODES 100000
#define KNBR 32
#define IN_C 128
#define OUT_C 64
#define CH_CHUNK 32                      // channels per chunk
#define NCHUNK (OUT_C / CH_CHUNK)        // 2
#define NODE_BLK 32                      // nodes per median block
#define NBLK (NNODES / NODE_BLK)         // 3125

typedef int   v4i __attribute__((ext_vector_type(4)));
typedef float v4f __attribute__((ext_vector_type(4)));

// ======================= Kernel 1: h = x @ W^T (fp32 compute, fp16 store) ==
// Block 256 threads; tile = 64 nodes x 64 channels; K chunked by 64.
// LDS k-major tiles; row stride 72 floats: 72 mod 32 = 8 -> staging-write
// bank = (8c + nl) mod 32, conflict-free across the 16 lanes of a write;
// compute-read bank stride 4 over 16 lanes = 2-way = free. 288 B row = 16B-aligned.
__global__ __launch_bounds__(256) void gemm_h_kernel(
    const float* __restrict__ x, const float* __restrict__ W,
    __half* __restrict__ h)
{
    __shared__ __align__(16) float sx[64 * 72];
    __shared__ __align__(16) float sw[64 * 72];

    const int t = threadIdx.x;
    const int node0 = blockIdx.x * 64;
    const int tx = t & 15;   // channel quad: channels 4*tx..4*tx+3
    const int ty = t >> 4;   // node quad:    nodes    4*ty..4*ty+3
    const int kq = t & 15;   // staging k-quad
    const int sl = t >> 4;   // staging row base

    float acc[4][4];
#pragma unroll
    for (int i = 0; i < 4; ++i)
#pragma unroll
        for (int j = 0; j < 4; ++j) acc[i][j] = 0.f;

    for (int kc = 0; kc < 2; ++kc) {
        const int kbase = kc * 64;
        __syncthreads();
#pragma unroll
        for (int pass = 0; pass < 4; ++pass) {
            const int nl = sl + pass * 16;           // 0..63
            int nn = node0 + nl;
            if (nn > NNODES - 1) nn = NNODES - 1;    // clamp tail reads
            const float4 xv = *(const float4*)(x + nn * IN_C + kbase + 4 * kq);
            sx[(4 * kq + 0) * 72 + nl] = xv.x;
            sx[(4 * kq + 1) * 72 + nl] = xv.y;
            sx[(4 * kq + 2) * 72 + nl] = xv.z;
            sx[(4 * kq + 3) * 72 + nl] = xv.w;
            const float4 wv = *(const float4*)(W + nl * IN_C + kbase + 4 * kq);
            sw[(4 * kq + 0) * 72 + nl] = wv.x;
            sw[(4 * kq + 1) * 72 + nl] = wv.y;
            sw[(4 * kq + 2) * 72 + nl] = wv.z;
            sw[(4 * kq + 3) * 72 + nl] = wv.w;
        }
        __syncthreads();
#pragma unroll 8
        for (int kk = 0; kk < 64; ++kk) {
            const float4 wv = *(const float4*)&sw[kk * 72 + 4 * tx];
            const float4 xv = *(const float4*)&sx[kk * 72 + 4 * ty];
            acc[0][0] += xv.x * wv.x; acc[0][1] += xv.x * wv.y;
            acc[0][2] += xv.x * wv.z; acc[0][3] += xv.x * wv.w;
            acc[1][0] += xv.y * wv.x; acc[1][1] += xv.y * wv.y;
            acc[1][2] += xv.y * wv.z; acc[1][3] += xv.y * wv.w;
            acc[2][0] += xv.z * wv.x; acc[2][1] += xv.z * wv.y;
            acc[2][2] += xv.z * wv.z; acc[2][3] += xv.z * wv.w;
            acc[3][0] += xv.w * wv.x; acc[3][1] += xv.w * wv.y;
            acc[3][2] += xv.w * wv.z; acc[3][3] += xv.w * wv.w;
        }
    }
    // chunk-major store: h[chunk][node][32]; thread's 4 channels live in one chunk
    const int cch = tx >> 3;             // channel chunk (0/1)
    const int off = (4 * tx) & 31;       // offset within chunk
#pragma unroll
    for (int i = 0; i < 4; ++i) {
        const int node = node0 + 4 * ty + i;
        if (node < NNODES) {
            __half2 p0 = __floats2half2_rn(acc[i][0], acc[i][1]);
            __half2 p1 = __floats2half2_rn(acc[i][2], acc[i][3]);
            uint2 st;
            st.x = *(unsigned int*)&p0;
            st.y = *(unsigned int*)&p1;
            *(uint2*)(h + (size_t)cch * (NNODES * CH_CHUNK) + node * CH_CHUNK + off) = st;
        }
    }
}

// ======================= Kernel 2: gather + rank-15-of-32 ==================
// Packed half2 min/max via gfx950 VOP3P — ROCm 7.2 headers lack __hmin2/__hmax2.
__device__ __forceinline__ unsigned pk_min(unsigned a, unsigned b) {
    unsigned d;
    asm("v_pk_min_f16 %0, %1, %2" : "=v"(d) : "v"(a), "v"(b));
    return d;
}
__device__ __forceinline__ unsigned pk_max(unsigned a, unsigned b) {
    unsigned d;
    asm("v_pk_max_f16 %0, %1, %2" : "=v"(d) : "v"(a), "v"(b));
    return d;
}
__device__ __forceinline__ void ce(unsigned& a, unsigned& b) {
    const unsigned lo = pk_min(a, b);
    b = pk_max(a, b);
    a = lo;
}

// Batcher odd-even mergesort, n=16, 63 comparators (hardcoded list).
__device__ __forceinline__ void sort16(unsigned* v) {
    constexpr unsigned char net[63][2] = {
        {0,1},{2,3},{4,5},{6,7},{8,9},{10,11},{12,13},{14,15},
        {0,2},{1,3},{4,6},{5,7},{8,10},{9,11},{12,14},{13,15},
        {1,2},{5,6},{9,10},{13,14},
        {0,4},{1,5},{2,6},{3,7},{8,12},{9,13},{10,14},{11,15},
        {2,4},{3,5},{10,12},{11,13},
        {1,2},{3,4},{5,6},{9,10},{11,12},{13,14},
        {0,8},{1,9},{2,10},{3,11},{4,12},{5,13},{6,14},{7,15},
        {4,8},{5,9},{6,10},{7,11},
        {2,4},{3,5},{6,8},{7,9},{10,12},{11,13},
        {1,2},{3,4},{5,6},{7,8},{9,10},{11,12},{13,14}
    };
#pragma unroll
    for (int i = 0; i < 63; ++i) ce(v[net[i][0]], v[net[i][1]]);
}

// rank 15 (0-indexed) of 32 values: sort both 16-halves, then a pruned
// Batcher odd-even merge that materializes only output 15.
__device__ __forceinline__ unsigned median32(unsigned* v) {
    sort16(v);
    sort16(v + 16);
    const unsigned* A = v;
    const unsigned* B = v + 16;
    const unsigned e2a = pk_max(pk_max(A[0], B[0]), pk_min(A[8],  B[8]));
    const unsigned o1a = pk_min(pk_max(A[4], B[4]), pk_min(A[12], B[12]));
    const unsigned Ep4 = pk_max(e2a, o1a);
    const unsigned e2b = pk_max(pk_max(A[2], B[2]), pk_min(A[10], B[10]));
    const unsigned o1b = pk_min(pk_max(A[6], B[6]), pk_min(A[14], B[14]));
    const unsigned Op3 = pk_min(e2b, o1b);
    const unsigned E8  = pk_max(Ep4, Op3);
    const unsigned e2c = pk_max(pk_max(A[1], B[1]), pk_min(A[9],  B[9]));
    const unsigned o1c = pk_min(pk_max(A[5], B[5]), pk_min(A[13], B[13]));
    const unsigned Ep4o = pk_max(e2c, o1c);
    const unsigned e2d = pk_max(pk_max(A[3], B[3]), pk_min(A[11], B[11]));
    const unsigned o1d = pk_min(pk_max(A[7], B[7]), pk_min(A[15], B[15]));
    const unsigned Op3o = pk_min(e2d, o1d);
    const unsigned O7  = pk_min(Ep4o, Op3o);
    return pk_min(E8, O7);
}

// 8 lanes per node, one 32-channel chunk per block; each lane owns 4 channels
// as two packed-half2 streams. Grid is chunk-major (all blocks of chunk 0
// dispatch first) so the live h-slice is 6.4 MB -> mostly per-XCD L2 resident.
// nbrs/out use nontemporal accesses to avoid evicting the slice.
__global__ __launch_bounds__(256) void median_kernel(
    const __half* __restrict__ h, const int* __restrict__ nbrs,
    float* __restrict__ out)
{
    const int t = threadIdx.x;
    const int li = t & 7;                        // lane within node
    const int c  = blockIdx.x / NBLK;            // channel chunk (0/1)
    const int nb = blockIdx.x % NBLK;
    const int node = nb * NODE_BLK + (t >> 3);
    const int ch0 = 4 * li;                      // channel offset within chunk

    // 8 lanes x int4 = this node's 32 neighbor indices
    const v4i idx = __builtin_nontemporal_load(
        (const v4i*)(nbrs + node * KNBR + 4 * li));

    const __half* hc = h + (size_t)c * (NNODES * CH_CHUNK);

    unsigned a[KNBR];  // channels ch0, ch0+1
    unsigned b[KNBR];  // channels ch0+2, ch0+3
#pragma unroll
    for (int k = 0; k < KNBR; ++k) {
        const int row = __shfl(idx[k & 3], k >> 2, 8);
        const uint2 rv = *(const uint2*)(hc + row * CH_CHUNK + ch0);
        a[k] = rv.x;
        b[k] = rv.y;
    }

    const unsigned ma = median32(a);
    const unsigned mb = median32(b);
    const __half2 ha = *(const __half2*)&ma;
    const __half2 hb = *(const __half2*)&mb;

    v4f o;
    o.x = __low2float(ha);
    o.y = __high2float(ha);
    o.z = __low2float(hb);
    o.w = __high2float(hb);
    __builtin_nontemporal_store(o, (v4f*)(out + node * OUT_C + c * CH_CHUNK + ch0));
}

extern "C" void kernel_launch(void* const* d_in, const int* in_sizes, int n_in,
                              void* d_out, int out_size, void* d_ws, size_t ws_size,
                              hipStream_t stream) {
    (void)in_sizes; (void)n_in; (void)out_size; (void)ws_size;
    const float* x    = (const float*)d_in[0];
    const int*   nbrs = (const int*)d_in[1];
    const float* W    = (const float*)d_in[2];
    float* out = (float*)d_out;
    __half* h  = (__half*)d_ws;   // 100000*64*2 = 12.8 MB scratch (chunk-major)

    gemm_h_kernel<<<(NNODES + 63) / 64, 256, 0, stream>>>(x, W, h);
    median_kernel<<<NCHUNK * NBLK, 256, 0, stream>>>(h, nbrs, out);
}

// Round 5
// 163.592 us; speedup vs baseline: 1.1103x; 1.1103x over previous
//
#include <hip/hip_runtime.h>
#include <hip/hip_fp16.h>

#define NNODES 100000
#define KNBR 32
#define IN_C 128
#define OUT_C 64
#define NTILES (NNODES / 16)   // 6250, exact

typedef _Float16 half8  __attribute__((ext_vector_type(8)));
typedef __fp16   fp16x2 __attribute__((ext_vector_type(2)));  // cvt_pkrtz return type
typedef float    f4     __attribute__((ext_vector_type(4)));

union H8 { half8 v; fp16x2 h2[4]; };

// 8 consecutive fp32 -> one 8xf16 MFMA fragment (v_cvt_pkrtz_f16_f32).
__device__ __forceinline__ half8 load_frag_f32(const float* p) {
    const float4 a = *(const float4*)p;
    const float4 b = *(const float4*)(p + 4);
    H8 r;
    r.h2[0] = __builtin_amdgcn_cvt_pkrtz(a.x, a.y);
    r.h2[1] = __builtin_amdgcn_cvt_pkrtz(a.z, a.w);
    r.h2[2] = __builtin_amdgcn_cvt_pkrtz(b.x, b.y);
    r.h2[3] = __builtin_amdgcn_cvt_pkrtz(b.z, b.w);
    return r.v;
}

// ============ Kernel 1: h = x @ W^T via mfma_f32_16x16x32_f16, no LDS ======
// One wave per 16-node tile; 64 output channels = 4 n-blocks; K=128 = 4 chunks.
// A[m=lane&15][k=(lane>>4)*8+j] from x; B[k][n=lane&15] = W[n][k] (same
// addressing pattern as A, from W rows). W fragments (64 VGPRs) preloaded.
// C/D: col=lane&15, row=(lane>>4)*4+reg  [HW-verified mapping].
__global__ __launch_bounds__(64) void gemm_h_kernel(
    const float* __restrict__ x, const float* __restrict__ W,
    __half* __restrict__ h)
{
    const int l = threadIdx.x;
    const int m = l & 15;        // node-in-tile (A) / channel-in-block (B)
    const int q = l >> 4;        // k-subgroup
    const int node0 = blockIdx.x * 16;

    half8 wf[4][4];              // [n-block][k-chunk]
#pragma unroll
    for (int b = 0; b < 4; ++b)
#pragma unroll
        for (int kc = 0; kc < 4; ++kc)
            wf[b][kc] = load_frag_f32(W + (16 * b + m) * IN_C + kc * 32 + 8 * q);

    f4 acc[4] = {};
#pragma unroll
    for (int kc = 0; kc < 4; ++kc) {
        const half8 af = load_frag_f32(x + (size_t)(node0 + m) * IN_C + kc * 32 + 8 * q);
#pragma unroll
        for (int b = 0; b < 4; ++b)
            acc[b] = __builtin_amdgcn_mfma_f32_16x16x32_f16(af, wf[b][kc], acc[b], 0, 0, 0);
    }

    // acc[b][r] -> h[node0 + 4q + r][16b + m]; 16 lanes -> 32B segments.
#pragma unroll
    for (int b = 0; b < 4; ++b)
#pragma unroll
        for (int r = 0; r < 4; ++r)
            h[(node0 + 4 * q + r) * OUT_C + 16 * b + m] = __float2half(acc[b][r]);
}

// ======================= Kernel 2: gather + rank-15-of-32 ==================
// Packed half2 min/max via gfx950 VOP3P — ROCm 7.2 headers lack __hmin2/__hmax2.
__device__ __forceinline__ unsigned pk_min(unsigned a, unsigned b) {
    unsigned d;
    asm("v_pk_min_f16 %0, %1, %2" : "=v"(d) : "v"(a), "v"(b));
    return d;
}
__device__ __forceinline__ unsigned pk_max(unsigned a, unsigned b) {
    unsigned d;
    asm("v_pk_max_f16 %0, %1, %2" : "=v"(d) : "v"(a), "v"(b));
    return d;
}
__device__ __forceinline__ void ce(unsigned& a, unsigned& b) {
    const unsigned lo = pk_min(a, b);
    b = pk_max(a, b);
    a = lo;
}

// Batcher odd-even mergesort, n=16, 63 comparators.
__device__ __forceinline__ void sort16(unsigned* v) {
    constexpr unsigned char net[63][2] = {
        {0,1},{2,3},{4,5},{6,7},{8,9},{10,11},{12,13},{14,15},
        {0,2},{1,3},{4,6},{5,7},{8,10},{9,11},{12,14},{13,15},
        {1,2},{5,6},{9,10},{13,14},
        {0,4},{1,5},{2,6},{3,7},{8,12},{9,13},{10,14},{11,15},
        {2,4},{3,5},{10,12},{11,13},
        {1,2},{3,4},{5,6},{9,10},{11,12},{13,14},
        {0,8},{1,9},{2,10},{3,11},{4,12},{5,13},{6,14},{7,15},
        {4,8},{5,9},{6,10},{7,11},
        {2,4},{3,5},{6,8},{7,9},{10,12},{11,13},
        {1,2},{3,4},{5,6},{7,8},{9,10},{11,12},{13,14}
    };
#pragma unroll
    for (int i = 0; i < 63; ++i) ce(v[net[i][0]], v[net[i][1]]);
}

// rank 15 (0-indexed) of 32: sort both 16-halves + pruned odd-even merge
// materializing only output 15.
__device__ __forceinline__ unsigned median32(unsigned* v) {
    sort16(v);
    sort16(v + 16);
    const unsigned* A = v;
    const unsigned* B = v + 16;
    const unsigned e2a = pk_max(pk_max(A[0], B[0]), pk_min(A[8],  B[8]));
    const unsigned o1a = pk_min(pk_max(A[4], B[4]), pk_min(A[12], B[12]));
    const unsigned Ep4 = pk_max(e2a, o1a);
    const unsigned e2b = pk_max(pk_max(A[2], B[2]), pk_min(A[10], B[10]));
    const unsigned o1b = pk_min(pk_max(A[6], B[6]), pk_min(A[14], B[14]));
    const unsigned Op3 = pk_min(e2b, o1b);
    const unsigned E8  = pk_max(Ep4, Op3);
    const unsigned e2c = pk_max(pk_max(A[1], B[1]), pk_min(A[9],  B[9]));
    const unsigned o1c = pk_min(pk_max(A[5], B[5]), pk_min(A[13], B[13]));
    const unsigned Ep4o = pk_max(e2c, o1c);
    const unsigned e2d = pk_max(pk_max(A[3], B[3]), pk_min(A[11], B[11]));
    const unsigned o1d = pk_min(pk_max(A[7], B[7]), pk_min(A[15], B[15]));
    const unsigned Op3o = pk_min(e2d, o1d);
    const unsigned O7  = pk_min(Ep4o, Op3o);
    return pk_min(E8, O7);
}

// 16 lanes per node; lane owns 4 channels as two packed-half2 streams.
// h rows are 128B = exactly one cache line per gathered neighbor.
// Row indices broadcast within the 16-lane group via __shfl(width=16).
__global__ __launch_bounds__(256) void median_kernel(
    const __half* __restrict__ h, const int* __restrict__ nbrs,
    float* __restrict__ out)
{
    const int t = threadIdx.x;
    const int li = t & 15;
    const int node = blockIdx.x * 16 + (t >> 4);
    const int ch0 = 4 * li;

    const int ia = __builtin_nontemporal_load(nbrs + node * KNBR + li);
    const int ib = __builtin_nontemporal_load(nbrs + node * KNBR + 16 + li);

    unsigned a[KNBR];  // channels ch0, ch0+1
    unsigned b[KNBR];  // channels ch0+2, ch0+3
#pragma unroll
    for (int k = 0; k < KNBR; ++k) {
        const int row = (k < 16) ? __shfl(ia, k, 16) : __shfl(ib, k - 16, 16);
        const uint2 rv = *(const uint2*)(h + row * OUT_C + ch0);
        a[k] = rv.x;
        b[k] = rv.y;
    }

    const unsigned ma = median32(a);
    const unsigned mb = median32(b);
    const __half2 ha = *(const __half2*)&ma;
    const __half2 hb = *(const __half2*)&mb;

    f4 o;
    o.x = __low2float(ha);
    o.y = __high2float(ha);
    o.z = __low2float(hb);
    o.w = __high2float(hb);
    __builtin_nontemporal_store(o, (f4*)(out + node * OUT_C + ch0));
}

extern "C" void kernel_launch(void* const* d_in, const int* in_sizes, int n_in,
                              void* d_out, int out_size, void* d_ws, size_t ws_size,
                              hipStream_t stream) {
    (void)in_sizes; (void)n_in; (void)out_size; (void)ws_size;
    const float* x    = (const float*)d_in[0];
    const int*   nbrs = (const int*)d_in[1];
    const float* W    = (const float*)d_in[2];
    float* out = (float*)d_out;
    __half* h  = (__half*)d_ws;   // 100000*64*2 = 12.8 MB scratch, node-major

    gemm_h_kernel<<<NTILES, 64, 0, stream>>>(x, W, h);
    median_kernel<<<NNODES / 16, 256, 0, stream>>>(h, nbrs, out);
}